// Round 15
// baseline (180.788 us; speedup 1.0000x reference)
//
#include <hip/hip_runtime.h>
#include <math.h>

#define V 8192
#define D 128
#define NH 8
#define HD 16
#define SEQ 128
#define HID 341
#define EPS 1e-6f

__device__ __forceinline__ float sigm(float x) { return 1.0f / (1.0f + __expf(-x)); }

// 256-thread block-wide sum. scratch >= 4 floats. 2 barriers.
__device__ __forceinline__ float block_sum256(float v, float* scratch) {
    #pragma unroll
    for (int m = 32; m > 0; m >>= 1) v += __shfl_xor(v, m);
    if ((threadIdx.x & 63) == 0) scratch[threadIdx.x >> 6] = v;
    __syncthreads();
    float s = (scratch[0] + scratch[1]) + (scratch[2] + scratch[3]);
    __syncthreads();
    return s;
}

// 1024-thread block-wide sum. scratch >= 16 floats. 2 barriers.
__device__ __forceinline__ float block_sum1024(float v, float* scratch) {
    #pragma unroll
    for (int m = 32; m > 0; m >>= 1) v += __shfl_xor(v, m);
    if ((threadIdx.x & 63) == 0) scratch[threadIdx.x >> 6] = v;
    __syncthreads();
    float s = ((scratch[0] + scratch[1]) + (scratch[2] + scratch[3])) +
              ((scratch[4] + scratch[5]) + (scratch[6] + scratch[7])) +
              ((scratch[8] + scratch[9]) + (scratch[10] + scratch[11])) +
              ((scratch[12] + scratch[13]) + (scratch[14] + scratch[15]));
    __syncthreads();
    return s;
}

// device-scope grid barrier; slot-based (no reset). All NB blocks co-resident.
__device__ __forceinline__ void grid_bar(int* bar, int slot, int nb) {
    __syncthreads();
    if (threadIdx.x == 0) {
        __threadfence();  // release prior global writes
        __hip_atomic_fetch_add(&bar[slot], 1, __ATOMIC_ACQ_REL, __HIP_MEMORY_SCOPE_AGENT);
        while (__hip_atomic_load(&bar[slot], __ATOMIC_ACQUIRE, __HIP_MEMORY_SCOPE_AGENT) < nb) {
        }
        __threadfence();  // acquire side
    }
    __syncthreads();
}

// K1: embed + rms + qkv + rope. grid = SEQ + 256 (warm blocks), block=256
__global__ __launch_bounds__(256, 1) void k_embed_qkv(
    const int* __restrict__ idx, const float* __restrict__ w_raw,
    const float* __restrict__ wq, const float* __restrict__ wk,
    const float* __restrict__ wv, const float* __restrict__ n1w,
    const float* __restrict__ w1, const float* __restrict__ w3,
    const float* __restrict__ w2, const float* __restrict__ wo,
    float* __restrict__ x, float* __restrict__ q, float* __restrict__ k,
    float* __restrict__ v, float* __restrict__ sink, int* __restrict__ bar) {
    int t = threadIdx.x;
    if (blockIdx.x >= SEQ) {
        if (blockIdx.x == SEQ && t < 4) bar[t] = 0;  // init grid-barrier slots
        // L3-warm: stream every weight once (w_raw 4MB + layers ~1.8MB)
        int g = (blockIdx.x - SEQ) * 256 + t;  // 0..65535
        float acc = 0.f;
        const float4* p = (const float4*)w_raw;  // 262144 float4
        for (int i = g; i < 262144; i += 65536) {
            float4 u = p[i];
            acc += u.x + u.y + u.z + u.w;
        }
        p = (const float4*)w1;  // 21824 float4 (both layers)
        if (g < 21824) { float4 u = p[g]; acc += u.x + u.y + u.z + u.w; }
        p = (const float4*)w3;
        if (g < 21824) { float4 u = p[g]; acc += u.x + u.y + u.z + u.w; }
        p = (const float4*)w2;
        if (g < 21824) { float4 u = p[g]; acc += u.x + u.y + u.z + u.w; }
        p = (const float4*)wq;  // 8192 float4 (both layers)
        if (g < 8192) { float4 u = p[g]; acc += u.x + u.y + u.z + u.w; }
        p = (const float4*)wk;
        if (g < 8192) { float4 u = p[g]; acc += u.x + u.y + u.z + u.w; }
        p = (const float4*)wv;
        if (g < 8192) { float4 u = p[g]; acc += u.x + u.y + u.z + u.w; }
        p = (const float4*)wo;
        if (g < 8192) { float4 u = p[g]; acc += u.x + u.y + u.z + u.w; }
        if (acc == 1234.5678f) sink[0] = acc;  // never true; defeats DCE
        return;
    }
    __shared__ float hr[D], qrow[D], krow[D], vpart[2][D], scr[4];
    int s = blockIdx.x;
    int col = t & 127, half = t >> 7, dlo = half * 64;
    // embed gather (critical path) issued first
    float xv = 0.f;
    if (t < 128) xv = sigm(w_raw[t * V + idx[s]]);
    // prefetch QKV weight columns into registers (pure tid function)
    float wpre[128];
    const float* wsel = (t < 128) ? wq : wk;
    #pragma unroll
    for (int d = 0; d < 128; ++d) wpre[d] = wsel[d * D + col];
    float wvpre[64];
    #pragma unroll
    for (int d = 0; d < 64; ++d) wvpre[d] = wv[(dlo + d) * D + col];
    if (t < 128) x[s * D + t] = xv;
    float ss = block_sum256(xv * xv, scr);
    float r = 1.0f / sqrtf(ss * (1.0f / D) + EPS);
    if (t < 128) hr[t] = xv * r * n1w[t];
    __syncthreads();
    float a0 = 0, a1 = 0, a2 = 0, a3 = 0;
    #pragma unroll
    for (int d = 0; d < 128; d += 4) {
        a0 += hr[d] * wpre[d];
        a1 += hr[d + 1] * wpre[d + 1];
        a2 += hr[d + 2] * wpre[d + 2];
        a3 += hr[d + 3] * wpre[d + 3];
    }
    float qk = (a0 + a1) + (a2 + a3);
    float b0 = 0, b1 = 0, b2 = 0, b3 = 0;
    #pragma unroll
    for (int d = 0; d < 64; d += 4) {
        b0 += hr[dlo + d] * wvpre[d];
        b1 += hr[dlo + d + 1] * wvpre[d + 1];
        b2 += hr[dlo + d + 2] * wvpre[d + 2];
        b3 += hr[dlo + d + 3] * wvpre[d + 3];
    }
    vpart[half][col] = (b0 + b1) + (b2 + b3);
    if (t < 128) qrow[col] = qk;
    else krow[col] = qk;
    __syncthreads();
    if (t < 128) {
        v[s * D + t] = vpart[0][t] + vpart[1][t];
        int c = t & (HD - 1);
        int m = c >> 1;
        float fr = (float)s * expf(-(float)m * 1.15129254649702283e+00f);
        float cs = cosf(fr), sn = sinf(fr);
        int base = t & ~1;
        float qe = qrow[base], qod = qrow[base + 1];
        float ke = krow[base], kod = krow[base + 1];
        q[s * D + t] = (c & 1) ? (qe * sn + qod * cs) : (qe * cs - qod * sn);
        k[s * D + t] = (c & 1) ? (ke * sn + kod * cs) : (ke * cs - kod * sn);
    }
}

// layer body (1024 threads, R13 lean form: load-at-use, no prefetch arrays).
// MODE 0: k/v to global, rope'd q to qnext LDS, xr updated to post-FFN residual.
// MODE 1: writes normalized xng.
template <int MODE>
__device__ __forceinline__ void layer_body(
    int s, int t, float qv, float& xr,
    const float* __restrict__ kg, const float* __restrict__ vg,
    const float* __restrict__ wo, const float* __restrict__ n2w,
    const float* __restrict__ w1, const float* __restrict__ w3,
    const float* __restrict__ w2, const float* __restrict__ wq,
    const float* __restrict__ wk, const float* __restrict__ wv,
    const float* __restrict__ n1w, float* __restrict__ ko, float* __restrict__ vo,
    const float* __restrict__ fw, float* __restrict__ xng,
    float* ps /*NH*(SEQ+1)*/, float* qs, float* orow, float* h2,
    float* part /*8*D*/, float* afA, float* afB, float* af,
    float* rl, float* scr, float* qnext) {
    int col = t & 127, g8 = t >> 7;  // g8 in 0..7
    int jlo = g8 * 16, dlo = g8 * 16;

    if (t < 128) qs[t] = qv;
    __syncthreads();

    // scores: thread (j=col, h=g8), 16-deep dot; zero-fill j>s
    {
        const float4* kp = (const float4*)&kg[col * D + g8 * HD];
        float4 k0 = kp[0], k1v = kp[1], k2v = kp[2], k3v = kp[3];
        const float* qh = &qs[g8 * HD];
        float acc = k0.x * qh[0] + k0.y * qh[1] + k0.z * qh[2] + k0.w * qh[3] +
                    k1v.x * qh[4] + k1v.y * qh[5] + k1v.z * qh[6] + k1v.w * qh[7] +
                    k2v.x * qh[8] + k2v.y * qh[9] + k2v.z * qh[10] + k2v.w * qh[11] +
                    k3v.x * qh[12] + k3v.y * qh[13] + k3v.z * qh[14] + k3v.w * qh[15];
        ps[g8 * (SEQ + 1) + col] = (col <= s) ? acc * 0.25f : 0.f;
    }
    __syncthreads();

    // softmax over j<=s: waves 0..7, head h = t>>6, full wave per head
    if (t < 512) {
        int h = t >> 6, lane = t & 63;
        float pm = -1e30f;
        for (int j = lane; j <= s; j += 64) pm = fmaxf(pm, ps[h * (SEQ + 1) + j]);
        #pragma unroll
        for (int m = 32; m > 0; m >>= 1) pm = fmaxf(pm, __shfl_xor(pm, m));
        float psum = 0.f;
        for (int j = lane; j <= s; j += 64) {
            float e = __expf(ps[h * (SEQ + 1) + j] - pm);
            ps[h * (SEQ + 1) + j] = e;
            psum += e;
        }
        #pragma unroll
        for (int m = 32; m > 0; m >>= 1) psum += __shfl_xor(psum, m);
        if (lane == 0) rl[h] = 1.0f / psum;
    }
    __syncthreads();

    // o partials: h = col>>4, j in [jlo, jlo+16); V loaded at use (coalesced)
    {
        int h = col >> 4;
        float a0 = 0, a1 = 0, a2 = 0, a3 = 0;
        #pragma unroll
        for (int j = 0; j < 16; j += 4) {
            a0 += ps[h * (SEQ + 1) + jlo + j] * vg[(jlo + j) * D + col];
            a1 += ps[h * (SEQ + 1) + jlo + j + 1] * vg[(jlo + j + 1) * D + col];
            a2 += ps[h * (SEQ + 1) + jlo + j + 2] * vg[(jlo + j + 2) * D + col];
            a3 += ps[h * (SEQ + 1) + jlo + j + 3] * vg[(jlo + j + 3) * D + col];
        }
        part[g8 * D + col] = (a0 + a1) + (a2 + a3);
    }
    __syncthreads();
    if (t < 128)
        orow[t] = (((part[t] + part[D + t]) + (part[2 * D + t] + part[3 * D + t])) +
                   ((part[4 * D + t] + part[5 * D + t]) +
                    (part[6 * D + t] + part[7 * D + t]))) * rl[t >> 4];
    __syncthreads();

    // wo: u in [dlo, dlo+16), loaded at use (coalesced)
    {
        float a0 = 0, a1 = 0;
        #pragma unroll
        for (int u = 0; u < 16; u += 2) {
            a0 += orow[dlo + u] * wo[(dlo + u) * D + col];
            a1 += orow[dlo + u + 1] * wo[(dlo + u + 1) * D + col];
        }
        part[g8 * D + col] = a0 + a1;
    }
    __syncthreads();
    float xn = 0.f;
    if (t < 128)
        xn = xr + ((part[t] + part[D + t]) + (part[2 * D + t] + part[3 * D + t])) +
             ((part[4 * D + t] + part[5 * D + t]) + (part[6 * D + t] + part[7 * D + t]));
    float ss2 = block_sum1024((t < 128) ? xn * xn : 0.f, scr);
    float r2 = 1.0f / sqrtf(ss2 * (1.0f / D) + EPS);
    if (t < 128) h2[t] = xn * r2 * n2w[t];
    __syncthreads();

    // FFN1: 682 column-tasks, SINGLE round (t < 682)
    if (t < 2 * HID) {
        int mat = t >= HID;
        int c2 = mat ? (t - HID) : t;
        const float* w = mat ? w3 : w1;
        float a0 = 0, a1 = 0, a2 = 0, a3 = 0;
        #pragma unroll 8
        for (int d = 0; d < D; d += 4) {
            a0 += h2[d] * w[d * HID + c2];
            a1 += h2[d + 1] * w[(d + 1) * HID + c2];
            a2 += h2[d + 2] * w[(d + 2) * HID + c2];
            a3 += h2[d + 3] * w[(d + 3) * HID + c2];
        }
        if (mat) afB[c2] = (a0 + a1) + (a2 + a3);
        else afA[c2] = (a0 + a1) + (a2 + a3);
    }
    __syncthreads();
    if (t < HID) {
        float a1v = afA[t];
        af[t] = (a1v / (1.0f + __expf(-a1v))) * afB[t];
    }
    __syncthreads();

    // FFN2: col output, 341-sum split 8-way (43 each, last 40)
    {
        int lo = g8 * 43;
        int hi = (lo + 43 > HID) ? HID : lo + 43;
        float a0 = 0, a1 = 0, a2 = 0, a3 = 0;
        int tt = lo;
        #pragma unroll 8
        for (; tt + 3 < hi; tt += 4) {
            a0 += af[tt] * w2[tt * D + col];
            a1 += af[tt + 1] * w2[(tt + 1) * D + col];
            a2 += af[tt + 2] * w2[(tt + 2) * D + col];
            a3 += af[tt + 3] * w2[(tt + 3) * D + col];
        }
        for (; tt < hi; ++tt) a0 += af[tt] * w2[tt * D + col];
        part[g8 * D + col] = (a0 + a1) + (a2 + a3);
    }
    __syncthreads();
    float x2 = 0.f;
    if (t < 128)
        x2 = xn + ((part[t] + part[D + t]) + (part[2 * D + t] + part[3 * D + t])) +
             ((part[4 * D + t] + part[5 * D + t]) + (part[6 * D + t] + part[7 * D + t]));

    float ss = block_sum1024((t < 128) ? x2 * x2 : 0.f, scr);
    float r = 1.0f / sqrtf(ss * (1.0f / D) + EPS);

    if constexpr (MODE == 0) {
        xr = x2;  // residual carried in register to next layer
        if (t < 128) h2[t] = x2 * r * n1w[t];
        __syncthreads();
        // next-layer QKV: groups 0=q, 1=k, 2=v (full 128-deep dots), 3..7 idle
        float qk = 0.f;
        if (g8 < 3) {
            const float* wsel = (g8 == 0) ? wq : ((g8 == 1) ? wk : wv);
            float a0 = 0, a1 = 0, a2 = 0, a3 = 0;
            #pragma unroll 8
            for (int d = 0; d < D; d += 4) {
                a0 += h2[d] * wsel[d * D + col];
                a1 += h2[d + 1] * wsel[(d + 1) * D + col];
                a2 += h2[d + 2] * wsel[(d + 2) * D + col];
                a3 += h2[d + 3] * wsel[(d + 3) * D + col];
            }
            qk = (a0 + a1) + (a2 + a3);
        }
        if (g8 == 0) qs[col] = qk;
        else if (g8 == 1) orow[col] = qk;
        else if (g8 == 2) part[col] = qk;
        __syncthreads();
        if (t < 128) {
            vo[s * D + t] = part[t];  // v to global (cross-row consumer)
            int c = t & (HD - 1);
            int mm = c >> 1;
            float fr = (float)s * expf(-(float)mm * 1.15129254649702283e+00f);
            float cs = cosf(fr), sn = sinf(fr);
            int base = t & ~1;
            float qe = qs[base], qod = qs[base + 1];
            float ke = orow[base], kod = orow[base + 1];
            qnext[t] = (c & 1) ? (qe * sn + qod * cs) : (qe * cs - qod * sn);
            ko[s * D + t] = (c & 1) ? (ke * sn + kod * cs) : (ke * cs - kod * sn);
        }
    } else {
        float y = (t < 128) ? x2 * r * fw[t] : 0.f;
        float nn = block_sum1024(y * y, scr);
        if (t < 128) xng[t * SEQ + s] = y / sqrtf(nn);
    }
}

// Fused: layer0 -> grid barrier -> layer1 -> grid barrier -> logits.
// grid = 128 x 1024 (all co-resident; lean body, no prefetch arrays).
__global__ __launch_bounds__(1024, 4) void k_fused(
    const float* __restrict__ q1, const float* __restrict__ k1,
    const float* __restrict__ v1, const float* __restrict__ x,
    const float* __restrict__ wq, const float* __restrict__ wk,
    const float* __restrict__ wv, const float* __restrict__ wo,
    const float* __restrict__ n1w, const float* __restrict__ n2w,
    const float* __restrict__ w1, const float* __restrict__ w3,
    const float* __restrict__ w2, const float* __restrict__ fw,
    const float* __restrict__ w_raw, float* __restrict__ k2g,
    float* __restrict__ v2g, float* __restrict__ xng, float* __restrict__ out,
    int* __restrict__ bar) {
    __shared__ float ps[NH * (SEQ + 1)];
    __shared__ float qs[D], orow[D], h2[D], qnext[D];
    __shared__ float part[8 * D];
    __shared__ float afA[HID], afB[HID], af[HID];
    __shared__ float rl[NH];
    __shared__ float scr[16];
    __shared__ __align__(16) float vs[D * 64];  // 32 KB logits chunk
    __shared__ float nred[1024];
    __shared__ float invn_s[64];

    int bid = blockIdx.x, t = threadIdx.x;
    int s = bid;
    float xr = 0.f, qv = 0.f;
    if (t < 128) {
        qv = q1[s * D + t];
        xr = x[s * D + t];
    }
    layer_body<0>(s, t, qv, xr, k1, v1, wo, n2w, w1, w3, w2,
                  wq + D * D, wk + D * D, wv + D * D, n1w + D, k2g, v2g,
                  (const float*)nullptr, (float*)nullptr,
                  ps, qs, orow, h2, part, afA, afB, af, rl, scr, qnext);
    grid_bar(bar, 0, SEQ);
    qv = (t < 128) ? qnext[t] : 0.f;
    layer_body<1>(s, t, qv, xr, k2g, v2g, wo + D * D, n2w + D, w1 + D * HID,
                  w3 + D * HID, w2 + HID * D, (const float*)nullptr,
                  (const float*)nullptr, (const float*)nullptr,
                  (const float*)nullptr, (float*)nullptr, (float*)nullptr, fw, xng,
                  ps, qs, orow, h2, part, afA, afB, af, rl, scr, qnext);
    grid_bar(bar, 1, SEQ);

    // logits: block owns vbase = bid*64 (128 blocks x 64 = 8192 v).
    // xng (64 KB, L2/L3-resident) read directly from global.
    {
        int vbase = bid * 64;
        for (int i = t; i < D * 64; i += 1024) {
            int d = i >> 6, jj = i & 63;
            vs[i] = sigm(w_raw[d * V + vbase + jj]);
        }
        __syncthreads();
        {
            int colc = t & 63, dp = t >> 6;  // 16 d-chunks of 8
            float p = 0.f;
            #pragma unroll
            for (int u = 0; u < 8; ++u) {
                float vv = vs[(dp * 8 + u) * 64 + colc];
                p += vv * vv;
            }
            nred[t] = p;
        }
        __syncthreads();
        if (t < 64) {
            float sum = 0.f;
            #pragma unroll
            for (int u = 0; u < 16; ++u) sum += nred[u * 64 + t];
            invn_s[t] = 1.0f / sqrtf(sum);
        }
        __syncthreads();
        for (int i = t; i < D * 64; i += 1024) vs[i] *= invn_s[i & 63];
        __syncthreads();
        int vg = t & 15;   // 16 groups x 4 v
        int sg = t >> 4;   // 64 groups x 2 s
        float acc[2][4] = {};
        for (int d = 0; d < D; ++d) {
            float2 xq = *(const float2*)&xng[d * SEQ + sg * 2];
            float4 vq = *(const float4*)&vs[d * 64 + vg * 4];
            acc[0][0] += (xq.x <= vq.x) ? 1.0f : vq.x;
            acc[0][1] += (xq.x <= vq.y) ? 1.0f : vq.y;
            acc[0][2] += (xq.x <= vq.z) ? 1.0f : vq.z;
            acc[0][3] += (xq.x <= vq.w) ? 1.0f : vq.w;
            acc[1][0] += (xq.y <= vq.x) ? 1.0f : vq.x;
            acc[1][1] += (xq.y <= vq.y) ? 1.0f : vq.y;
            acc[1][2] += (xq.y <= vq.z) ? 1.0f : vq.z;
            acc[1][3] += (xq.y <= vq.w) ? 1.0f : vq.w;
        }
        const float inv128 = 1.0f / 128.0f;
        #pragma unroll
        for (int si = 0; si < 2; ++si) {
            int srow = sg * 2 + si;
            float4 ov;
            ov.x = fminf(fmaxf(acc[si][0] * inv128, 1e-6f), 1.0f - 1e-6f);
            ov.y = fminf(fmaxf(acc[si][1] * inv128, 1e-6f), 1.0f - 1e-6f);
            ov.z = fminf(fmaxf(acc[si][2] * inv128, 1e-6f), 1.0f - 1e-6f);
            ov.w = fminf(fmaxf(acc[si][3] * inv128, 1e-6f), 1.0f - 1e-6f);
            *(float4*)&out[srow * V + vbase + vg * 4] = ov;
        }
    }
}

extern "C" void kernel_launch(void* const* d_in, const int* in_sizes, int n_in,
                              void* d_out, int out_size, void* d_ws, size_t ws_size,
                              hipStream_t stream) {
    const int* idx = (const int*)d_in[0];
    const float* w_raw = (const float*)d_in[1];
    const float* n1w = (const float*)d_in[2];
    const float* n2w = (const float*)d_in[3];
    const float* wq = (const float*)d_in[4];
    const float* wk = (const float*)d_in[5];
    const float* wv = (const float*)d_in[6];
    const float* wo = (const float*)d_in[7];
    const float* w1 = (const float*)d_in[8];
    const float* w3 = (const float*)d_in[9];
    const float* w2 = (const float*)d_in[10];
    const float* fnw = (const float*)d_in[11];
    float* out = (float*)d_out;
    float* ws = (float*)d_ws;

    float* x    = ws;
    float* q1   = ws + 16384;
    float* k1   = ws + 32768;
    float* v1   = ws + 49152;
    float* k2   = ws + 81920;
    float* v2   = ws + 98304;
    float* xng  = ws + 114688;
    float* sink = ws + 131072;
    int*   bar  = (int*)(ws + 131080);

    k_embed_qkv<<<dim3(SEQ + 256), dim3(256), 0, stream>>>(
        idx, w_raw, wq, wk, wv, n1w, w1, w3, w2, wo, x, q1, k1, v1, sink, bar);
    k_fused<<<dim3(SEQ), dim3(1024), 0, stream>>>(
        q1, k1, v1, x, wq, wk, wv, wo, n1w, n2w, w1, w3, w2, fnw, w_raw,
        k2, v2, xng, out, bar);
}

// Round 16
// 139.051 us; speedup vs baseline: 1.3002x; 1.3002x over previous
//
#include <hip/hip_runtime.h>
#include <math.h>

#define V 8192
#define D 128
#define NH 8
#define HD 16
#define SEQ 128
#define HID 341
#define EPS 1e-6f

__device__ __forceinline__ float sigm(float x) { return 1.0f / (1.0f + __expf(-x)); }

// 256-thread block-wide sum. scratch >= 4 floats. 2 barriers.
__device__ __forceinline__ float block_sum256(float v, float* scratch) {
    #pragma unroll
    for (int m = 32; m > 0; m >>= 1) v += __shfl_xor(v, m);
    if ((threadIdx.x & 63) == 0) scratch[threadIdx.x >> 6] = v;
    __syncthreads();
    float s = (scratch[0] + scratch[1]) + (scratch[2] + scratch[3]);
    __syncthreads();
    return s;
}

// 1024-thread block-wide sum. scratch >= 16 floats. 2 barriers.
__device__ __forceinline__ float block_sum1024(float v, float* scratch) {
    #pragma unroll
    for (int m = 32; m > 0; m >>= 1) v += __shfl_xor(v, m);
    if ((threadIdx.x & 63) == 0) scratch[threadIdx.x >> 6] = v;
    __syncthreads();
    float s = ((scratch[0] + scratch[1]) + (scratch[2] + scratch[3])) +
              ((scratch[4] + scratch[5]) + (scratch[6] + scratch[7])) +
              ((scratch[8] + scratch[9]) + (scratch[10] + scratch[11])) +
              ((scratch[12] + scratch[13]) + (scratch[14] + scratch[15]));
    __syncthreads();
    return s;
}

// K1: embed + rms + qkv + rope. grid = SEQ + 256 (warm blocks), block=256
__global__ __launch_bounds__(256, 1) void k_embed_qkv(
    const int* __restrict__ idx, const float* __restrict__ w_raw,
    const float* __restrict__ wq, const float* __restrict__ wk,
    const float* __restrict__ wv, const float* __restrict__ n1w,
    const float* __restrict__ w1, const float* __restrict__ w3,
    const float* __restrict__ w2, const float* __restrict__ wo,
    float* __restrict__ x, float* __restrict__ q, float* __restrict__ k,
    float* __restrict__ v, float* __restrict__ sink) {
    int t = threadIdx.x;
    if (blockIdx.x >= SEQ) {
        // L3-warm: stream every weight once (w_raw 4MB + layers ~1.8MB)
        int g = (blockIdx.x - SEQ) * 256 + t;  // 0..65535
        float acc = 0.f;
        const float4* p = (const float4*)w_raw;  // 262144 float4
        for (int i = g; i < 262144; i += 65536) {
            float4 u = p[i];
            acc += u.x + u.y + u.z + u.w;
        }
        p = (const float4*)w1;  // 21824 float4 (both layers)
        if (g < 21824) { float4 u = p[g]; acc += u.x + u.y + u.z + u.w; }
        p = (const float4*)w3;
        if (g < 21824) { float4 u = p[g]; acc += u.x + u.y + u.z + u.w; }
        p = (const float4*)w2;
        if (g < 21824) { float4 u = p[g]; acc += u.x + u.y + u.z + u.w; }
        p = (const float4*)wq;  // 8192 float4 (both layers)
        if (g < 8192) { float4 u = p[g]; acc += u.x + u.y + u.z + u.w; }
        p = (const float4*)wk;
        if (g < 8192) { float4 u = p[g]; acc += u.x + u.y + u.z + u.w; }
        p = (const float4*)wv;
        if (g < 8192) { float4 u = p[g]; acc += u.x + u.y + u.z + u.w; }
        p = (const float4*)wo;
        if (g < 8192) { float4 u = p[g]; acc += u.x + u.y + u.z + u.w; }
        if (acc == 1234.5678f) sink[0] = acc;  // never true; defeats DCE
        return;
    }
    __shared__ float hr[D], qrow[D], krow[D], vpart[2][D], scr[4];
    int s = blockIdx.x;
    int col = t & 127, half = t >> 7, dlo = half * 64;
    // embed gather (critical path) issued first
    float xv = 0.f;
    if (t < 128) xv = sigm(w_raw[t * V + idx[s]]);
    // prefetch QKV weight columns into registers (pure tid function)
    float wpre[128];
    const float* wsel = (t < 128) ? wq : wk;
    #pragma unroll
    for (int d = 0; d < 128; ++d) wpre[d] = wsel[d * D + col];
    float wvpre[64];
    #pragma unroll
    for (int d = 0; d < 64; ++d) wvpre[d] = wv[(dlo + d) * D + col];
    if (t < 128) x[s * D + t] = xv;
    float ss = block_sum256(xv * xv, scr);
    float r = 1.0f / sqrtf(ss * (1.0f / D) + EPS);
    if (t < 128) hr[t] = xv * r * n1w[t];
    __syncthreads();
    float a0 = 0, a1 = 0, a2 = 0, a3 = 0;
    #pragma unroll
    for (int d = 0; d < 128; d += 4) {
        a0 += hr[d] * wpre[d];
        a1 += hr[d + 1] * wpre[d + 1];
        a2 += hr[d + 2] * wpre[d + 2];
        a3 += hr[d + 3] * wpre[d + 3];
    }
    float qk = (a0 + a1) + (a2 + a3);
    float b0 = 0, b1 = 0, b2 = 0, b3 = 0;
    #pragma unroll
    for (int d = 0; d < 64; d += 4) {
        b0 += hr[dlo + d] * wvpre[d];
        b1 += hr[dlo + d + 1] * wvpre[d + 1];
        b2 += hr[dlo + d + 2] * wvpre[d + 2];
        b3 += hr[dlo + d + 3] * wvpre[d + 3];
    }
    vpart[half][col] = (b0 + b1) + (b2 + b3);
    if (t < 128) qrow[col] = qk;
    else krow[col] = qk;
    __syncthreads();
    if (t < 128) {
        v[s * D + t] = vpart[0][t] + vpart[1][t];
        int c = t & (HD - 1);
        int m = c >> 1;
        float fr = (float)s * expf(-(float)m * 1.15129254649702283e+00f);
        float cs = cosf(fr), sn = sinf(fr);
        int base = t & ~1;
        float qe = qrow[base], qod = qrow[base + 1];
        float ke = krow[base], kod = krow[base + 1];
        q[s * D + t] = (c & 1) ? (qe * sn + qod * cs) : (qe * cs - qod * sn);
        k[s * D + t] = (c & 1) ? (ke * sn + kod * cs) : (ke * cs - kod * sn);
    }
}

// K2/K3: fused layer per row. grid=SEQ, block=1024 (16 waves, 4 waves/SIMD).
// No register-prefetch arrays (R11 lesson: compiler sinks/spills them);
// weights loaded at use with unrolled batching, latency hidden by 4-wave TLP.
template <int MODE>
__global__ __launch_bounds__(1024, 4) void k_layer(
    const float* __restrict__ q, const float* __restrict__ kg,
    const float* __restrict__ vg, float* __restrict__ x,
    const float* __restrict__ wo, const float* __restrict__ n2w,
    const float* __restrict__ w1, const float* __restrict__ w3,
    const float* __restrict__ w2, const float* __restrict__ wq,
    const float* __restrict__ wk, const float* __restrict__ wv,
    const float* __restrict__ n1w, float* __restrict__ qo, float* __restrict__ ko,
    float* __restrict__ vo, const float* __restrict__ fw, float* __restrict__ xng) {
    __shared__ float ps[NH][SEQ + 1];
    __shared__ float qs[D], orow[D], h2[D];
    __shared__ float part[8][D];
    __shared__ float afA[HID], afB[HID], af[HID];
    __shared__ float rl[NH];
    __shared__ float scr[16];
    int s = blockIdx.x, t = threadIdx.x;
    int col = t & 127, g8 = t >> 7;  // g8 in 0..7
    int jlo = g8 * 16, dlo = g8 * 16;

    float qv = 0.f, xr = 0.f;
    if (t < 128) {
        qv = q[s * D + t];
        xr = x[s * D + t];
        qs[t] = qv;
    }
    __syncthreads();

    // scores: thread (j=col, h=g8), 16-deep dot; zero-fill j>s
    {
        const float4* kp = (const float4*)&kg[col * D + g8 * HD];
        float4 k0 = kp[0], k1v = kp[1], k2v = kp[2], k3v = kp[3];
        const float* qh = &qs[g8 * HD];
        float acc = k0.x * qh[0] + k0.y * qh[1] + k0.z * qh[2] + k0.w * qh[3] +
                    k1v.x * qh[4] + k1v.y * qh[5] + k1v.z * qh[6] + k1v.w * qh[7] +
                    k2v.x * qh[8] + k2v.y * qh[9] + k2v.z * qh[10] + k2v.w * qh[11] +
                    k3v.x * qh[12] + k3v.y * qh[13] + k3v.z * qh[14] + k3v.w * qh[15];
        ps[g8][col] = (col <= s) ? acc * 0.25f : 0.f;
    }
    __syncthreads();

    // softmax over j<=s: waves 0..7, head h = t>>6, full wave per head
    if (t < 512) {
        int h = t >> 6, lane = t & 63;
        float pm = -1e30f;
        for (int j = lane; j <= s; j += 64) pm = fmaxf(pm, ps[h][j]);
        #pragma unroll
        for (int m = 32; m > 0; m >>= 1) pm = fmaxf(pm, __shfl_xor(pm, m));
        float psum = 0.f;
        for (int j = lane; j <= s; j += 64) {
            float e = __expf(ps[h][j] - pm);
            ps[h][j] = e;
            psum += e;
        }
        #pragma unroll
        for (int m = 32; m > 0; m >>= 1) psum += __shfl_xor(psum, m);
        if (lane == 0) rl[h] = 1.0f / psum;
    }
    __syncthreads();

    // o partials: h = col>>4, j in [jlo, jlo+16); V loaded at use (coalesced)
    {
        int h = col >> 4;
        float a0 = 0, a1 = 0, a2 = 0, a3 = 0;
        #pragma unroll
        for (int j = 0; j < 16; j += 4) {
            a0 += ps[h][jlo + j] * vg[(jlo + j) * D + col];
            a1 += ps[h][jlo + j + 1] * vg[(jlo + j + 1) * D + col];
            a2 += ps[h][jlo + j + 2] * vg[(jlo + j + 2) * D + col];
            a3 += ps[h][jlo + j + 3] * vg[(jlo + j + 3) * D + col];
        }
        part[g8][col] = (a0 + a1) + (a2 + a3);
    }
    __syncthreads();
    if (t < 128)
        orow[t] = (((part[0][t] + part[1][t]) + (part[2][t] + part[3][t])) +
                   ((part[4][t] + part[5][t]) + (part[6][t] + part[7][t]))) * rl[t >> 4];
    __syncthreads();

    // wo: u in [dlo, dlo+16), loaded at use (coalesced)
    {
        float a0 = 0, a1 = 0;
        #pragma unroll
        for (int u = 0; u < 16; u += 2) {
            a0 += orow[dlo + u] * wo[(dlo + u) * D + col];
            a1 += orow[dlo + u + 1] * wo[(dlo + u + 1) * D + col];
        }
        part[g8][col] = a0 + a1;
    }
    __syncthreads();
    float xn = 0.f;
    if (t < 128)
        xn = xr + ((part[0][t] + part[1][t]) + (part[2][t] + part[3][t])) +
             ((part[4][t] + part[5][t]) + (part[6][t] + part[7][t]));
    float ss2 = block_sum1024((t < 128) ? xn * xn : 0.f, scr);
    float r2 = 1.0f / sqrtf(ss2 * (1.0f / D) + EPS);
    if (t < 128) h2[t] = xn * r2 * n2w[t];
    __syncthreads();

    // FFN1: 682 column-tasks, SINGLE round (t < 682)
    if (t < 2 * HID) {
        int mat = t >= HID;
        int c2 = mat ? (t - HID) : t;
        const float* w = mat ? w3 : w1;
        float a0 = 0, a1 = 0, a2 = 0, a3 = 0;
        #pragma unroll 8
        for (int d = 0; d < D; d += 4) {
            a0 += h2[d] * w[d * HID + c2];
            a1 += h2[d + 1] * w[(d + 1) * HID + c2];
            a2 += h2[d + 2] * w[(d + 2) * HID + c2];
            a3 += h2[d + 3] * w[(d + 3) * HID + c2];
        }
        if (mat) afB[c2] = (a0 + a1) + (a2 + a3);
        else afA[c2] = (a0 + a1) + (a2 + a3);
    }
    __syncthreads();
    if (t < HID) {
        float a1v = afA[t];
        af[t] = (a1v / (1.0f + __expf(-a1v))) * afB[t];
    }
    __syncthreads();

    // FFN2: col output, 341-sum split 8-way (43 each, last 40)
    {
        int lo = g8 * 43;
        int hi = (lo + 43 > HID) ? HID : lo + 43;
        float a0 = 0, a1 = 0, a2 = 0, a3 = 0;
        int tt = lo;
        #pragma unroll 8
        for (; tt + 3 < hi; tt += 4) {
            a0 += af[tt] * w2[tt * D + col];
            a1 += af[tt + 1] * w2[(tt + 1) * D + col];
            a2 += af[tt + 2] * w2[(tt + 2) * D + col];
            a3 += af[tt + 3] * w2[(tt + 3) * D + col];
        }
        for (; tt < hi; ++tt) a0 += af[tt] * w2[tt * D + col];
        part[g8][col] = (a0 + a1) + (a2 + a3);
    }
    __syncthreads();
    float x2 = 0.f;
    if (t < 128) {
        x2 = xn + ((part[0][t] + part[1][t]) + (part[2][t] + part[3][t])) +
             ((part[4][t] + part[5][t]) + (part[6][t] + part[7][t]));
        if (MODE == 0) x[s * D + t] = x2;
    }

    float ss = block_sum1024((t < 128) ? x2 * x2 : 0.f, scr);
    float r = 1.0f / sqrtf(ss * (1.0f / D) + EPS);

    if constexpr (MODE == 0) {
        if (t < 128) h2[t] = x2 * r * n1w[t];
        __syncthreads();
        // next-layer QKV: groups 0=q, 1=k, 2=v (full 128-deep dots), 3..7 idle
        float qk = 0.f;
        if (g8 < 3) {
            const float* wsel = (g8 == 0) ? wq : ((g8 == 1) ? wk : wv);
            float a0 = 0, a1 = 0, a2 = 0, a3 = 0;
            #pragma unroll 8
            for (int d = 0; d < D; d += 4) {
                a0 += h2[d] * wsel[d * D + col];
                a1 += h2[d + 1] * wsel[(d + 1) * D + col];
                a2 += h2[d + 2] * wsel[(d + 2) * D + col];
                a3 += h2[d + 3] * wsel[(d + 3) * D + col];
            }
            qk = (a0 + a1) + (a2 + a3);
        }
        if (g8 == 0) qs[col] = qk;
        else if (g8 == 1) orow[col] = qk;
        else if (g8 == 2) part[0][col] = qk;
        __syncthreads();
        if (t < 128) {
            vo[s * D + t] = part[0][t];
            int c = t & (HD - 1);
            int mm = c >> 1;
            float fr = (float)s * expf(-(float)mm * 1.15129254649702283e+00f);
            float cs = cosf(fr), sn = sinf(fr);
            int base = t & ~1;
            float qe = qs[base], qod = qs[base + 1];
            float ke = orow[base], kod = orow[base + 1];
            qo[s * D + t] = (c & 1) ? (qe * sn + qod * cs) : (qe * cs - qod * sn);
            ko[s * D + t] = (c & 1) ? (ke * sn + kod * cs) : (ke * cs - kod * sn);
        }
    } else {
        float y = (t < 128) ? x2 * r * fw[t] : 0.f;
        float nn = block_sum1024(y * y, scr);
        if (t < 128) xng[t * SEQ + s] = y / sqrtf(nn);
    }
}

// K4: logits[s,v] = clip(mean_d(xn[s,d] <= vn[v,d] ? 1 : vn[v,d]))
__global__ __launch_bounds__(256) void k_logits(const float* __restrict__ xng,
                                                const float* __restrict__ w_raw,
                                                float* __restrict__ out) {
    __shared__ float xs[D * 64];
    __shared__ float vs[D * 32];
    __shared__ float nred[256];
    __shared__ float invn_s[32];
    int t = threadIdx.x;
    int sbase = (blockIdx.x & 1) * 64;
    int vbase = (blockIdx.x >> 1) * 32;
    for (int i = t; i < D * 64; i += 256) {
        int d = i >> 6, s2 = i & 63;
        xs[i] = xng[d * SEQ + sbase + s2];
    }
    for (int i = t; i < D * 32; i += 256) {
        int d = i >> 5, jj = i & 31;
        vs[i] = sigm(w_raw[d * V + vbase + jj]);
    }
    __syncthreads();
    {
        int colc = t & 31, dp = t >> 5;
        float p = 0.f;
        for (int u = 0; u < 16; ++u) {
            float vv = vs[(dp * 16 + u) * 32 + colc];
            p += vv * vv;
        }
        nred[t] = p;
    }
    __syncthreads();
    if (t < 32) {
        float sum = 0.f;
        for (int u = 0; u < 8; ++u) sum += nred[u * 32 + t];
        invn_s[t] = 1.0f / sqrtf(sum);
    }
    __syncthreads();
    for (int i = t; i < D * 32; i += 256) vs[i] *= invn_s[i & 31];
    __syncthreads();
    int vg = t & 15;
    int sg = t >> 4;
    float acc[4][2] = {};
    for (int d = 0; d < D; ++d) {
        float4 xq = *(const float4*)&xs[d * 64 + sg * 4];
        float2 vq = *(const float2*)&vs[d * 32 + vg * 2];
        acc[0][0] += (xq.x <= vq.x) ? 1.0f : vq.x;
        acc[0][1] += (xq.x <= vq.y) ? 1.0f : vq.y;
        acc[1][0] += (xq.y <= vq.x) ? 1.0f : vq.x;
        acc[1][1] += (xq.y <= vq.y) ? 1.0f : vq.y;
        acc[2][0] += (xq.z <= vq.x) ? 1.0f : vq.x;
        acc[2][1] += (xq.z <= vq.y) ? 1.0f : vq.y;
        acc[3][0] += (xq.w <= vq.x) ? 1.0f : vq.x;
        acc[3][1] += (xq.w <= vq.y) ? 1.0f : vq.y;
    }
    const float inv128 = 1.0f / 128.0f;
    #pragma unroll
    for (int si = 0; si < 4; ++si) {
        int s = sbase + sg * 4 + si;
        float2 ov;
        ov.x = fminf(fmaxf(acc[si][0] * inv128, 1e-6f), 1.0f - 1e-6f);
        ov.y = fminf(fmaxf(acc[si][1] * inv128, 1e-6f), 1.0f - 1e-6f);
        *(float2*)&out[s * V + vbase + vg * 2] = ov;
    }
}

extern "C" void kernel_launch(void* const* d_in, const int* in_sizes, int n_in,
                              void* d_out, int out_size, void* d_ws, size_t ws_size,
                              hipStream_t stream) {
    const int* idx = (const int*)d_in[0];
    const float* w_raw = (const float*)d_in[1];
    const float* n1w = (const float*)d_in[2];
    const float* n2w = (const float*)d_in[3];
    const float* wq = (const float*)d_in[4];
    const float* wk = (const float*)d_in[5];
    const float* wv = (const float*)d_in[6];
    const float* wo = (const float*)d_in[7];
    const float* w1 = (const float*)d_in[8];
    const float* w3 = (const float*)d_in[9];
    const float* w2 = (const float*)d_in[10];
    const float* fnw = (const float*)d_in[11];
    float* out = (float*)d_out;
    float* ws = (float*)d_ws;

    float* x    = ws;
    float* q1   = ws + 16384;
    float* k1   = ws + 32768;
    float* v1   = ws + 49152;
    float* q2   = ws + 65536;
    float* k2   = ws + 81920;
    float* v2   = ws + 98304;
    float* xng  = ws + 114688;
    float* sink = ws + 131072;

    k_embed_qkv<<<dim3(SEQ + 256), dim3(256), 0, stream>>>(
        idx, w_raw, wq, wk, wv, n1w, w1, w3, w2, wo, x, q1, k1, v1, sink);
    k_layer<0><<<dim3(SEQ), dim3(1024), 0, stream>>>(
        q1, k1, v1, x, wo, n2w, w1, w3, w2,
        wq + D * D, wk + D * D, wv + D * D, n1w + D, q2, k2, v2,
        (const float*)nullptr, (float*)nullptr);
    k_layer<1><<<dim3(SEQ), dim3(1024), 0, stream>>>(
        q2, k2, v2, x, wo + D * D, n2w + D, w1 + D * HID, w3 + D * HID,
        w2 + HID * D, (const float*)nullptr, (const float*)nullptr,
        (const float*)nullptr, (const float*)nullptr, (float*)nullptr,
        (float*)nullptr, (float*)nullptr, fnw, xng);
    k_logits<<<dim3(512), dim3(256), 0, stream>>>(xng, w_raw, out);
}